// Round 1
// baseline (242.071 us; speedup 1.0000x reference)
//
#include <hip/hip_runtime.h>
#include <hip/hip_bf16.h>
#include <stdint.h>

// Problem constants: B=2, S=2048, D=1024, H=16, HD=64.
// ws layout (MB): 0 hid_bf | 8 wq | 10 wk | 12 wv | 14 wo | 16 q (8MB) | 24 k (8MB)
//                 | 32 vt (8MB) | 40 ctx (8MB);  out_pre(f32,16MB) aliases q+k @16MB.
// Total 48 MB.

typedef unsigned short ushort_t;
typedef short bf16x8 __attribute__((ext_vector_type(8)));
typedef float f32x4 __attribute__((ext_vector_type(4)));
typedef unsigned short ushort8 __attribute__((ext_vector_type(8)));

#define LOG2E 1.4426950408889634f

__device__ __forceinline__ ushort_t f2b(float f) {
  uint32_t x = __builtin_bit_cast(uint32_t, f);
  return (ushort_t)((x + 0x7FFFu + ((x >> 16) & 1u)) >> 16);
}

__device__ __forceinline__ void gload16(const void* gptr, void* ldsptr) {
  __builtin_amdgcn_global_load_lds(
      (const __attribute__((address_space(1))) uint32_t*)gptr,
      (__attribute__((address_space(3))) uint32_t*)ldsptr, 16, 0, 0);
}

// ---------------- cast fp32 -> bf16 (vectorized) ----------------
__global__ void cast_kernel(const float* __restrict__ src, ushort_t* __restrict__ dst, int n) {
  int i = (blockIdx.x * 256 + threadIdx.x) * 8;
  if (i >= n) return;
  const float4* s = (const float4*)(src + i);
  float4 a = s[0], b = s[1];
  ushort8 o = { f2b(a.x), f2b(a.y), f2b(a.z), f2b(a.w),
                f2b(b.x), f2b(b.y), f2b(b.z), f2b(b.w) };
  *(ushort8*)(dst + i) = o;
}

// ---------------- GEMM 128x128, BK=32, 4 waves (m97 structure) ----------------
// C[m,n] = sum_k A[m,k]*B[n,k]   (A,B row-major [.][1024] bf16)
// MODE 0: QK proj: epilogue bias + RoPE (+qscale), out (bh,s,hd) bf16
// MODE 1: V^T: A=Wv, B=hidden; epilogue bias; out (bh,hd,s) bf16
// MODE 2: Wo: epilogue bias + residual, out fp32 [m][n]
template<int MODE>
__global__ __launch_bounds__(256) void gemm128(
    const ushort_t* __restrict__ A, const ushort_t* __restrict__ B,
    const float* __restrict__ bias, const float* __restrict__ cosT,
    const float* __restrict__ sinT, const float* __restrict__ resid,
    void* __restrict__ outp, float qscale)
{
  constexpr int K = 1024;
  __shared__ uint4 As[512], Bs[512];   // 128 rows x 4 chunks(16B) each
  const int tid = threadIdx.x;
  const int wave = tid >> 6, lane = tid & 63;
  const int d = lane & 15, g = lane >> 4;
  const int m0 = blockIdx.x * 128, n0 = blockIdx.y * 128;
  const int wm = (wave >> 1) * 64, wn = (wave & 1) * 64;

  const ushort_t* ag = A + (size_t)(m0 + (tid >> 2)) * K + (tid & 3) * 8;
  const ushort_t* bg = B + (size_t)(n0 + (tid >> 2)) * K + (tid & 3) * 8;
  char* asd = (char*)As + wave * 1024;   // wave-uniform LDS dest
  char* bsd = (char*)Bs + wave * 1024;

  f32x4 acc[4][4] = {};

  for (int k0 = 0; k0 < K; k0 += 32) {
    __syncthreads();
    gload16(ag + k0, asd);
    gload16(ag + 64 * K + k0, asd + 4096);
    gload16(bg + k0, bsd);
    gload16(bg + 64 * K + k0, bsd + 4096);
    __syncthreads();
    bf16x8 af[4], bfr[4];
#pragma unroll
    for (int i = 0; i < 4; ++i)
      af[i] = __builtin_bit_cast(bf16x8, As[(wm + i * 16 + d) * 4 + g]);
#pragma unroll
    for (int j = 0; j < 4; ++j)
      bfr[j] = __builtin_bit_cast(bf16x8, Bs[(wn + j * 16 + d) * 4 + g]);
#pragma unroll
    for (int i = 0; i < 4; ++i)
#pragma unroll
      for (int j = 0; j < 4; ++j)
        acc[i][j] = __builtin_amdgcn_mfma_f32_16x16x32_bf16(af[i], bfr[j], acc[i][j], 0, 0, 0);
  }

  // C/D layout: lane, reg r -> row = g*4+r, col = d (within each 16x16 tile)
  if constexpr (MODE == 0) {
    ushort_t* O = (ushort_t*)outp;
    const int head_base = n0 + wn;      // multiple of 64 -> single head per wave
    const int h = head_base >> 6;
#pragma unroll
    for (int i = 0; i < 4; ++i) {
#pragma unroll
      for (int r = 0; r < 4; ++r) {
        const int m = m0 + wm + i * 16 + g * 4 + r;
        const int s = m & 2047, b = m >> 11;
#pragma unroll
        for (int j = 0; j < 4; ++j) {
          const int c = j * 16 + d;     // 0..63 within head
          const float v0 = acc[i][j][r] + bias[head_base + c];
          const float v1 = acc[i][j ^ 2][r] + bias[head_base + (c ^ 32)];
          const float rot = (c < 32) ? -v1 : v1;
          const float vr = (v0 * cosT[s * 64 + c] + rot * sinT[s * 64 + c]) * qscale;
          O[(size_t)(((b << 4) + h) * 2048 + s) * 64 + c] = f2b(vr);
        }
      }
    }
  } else if constexpr (MODE == 1) {
    ushort_t* O = (ushort_t*)outp;
#pragma unroll
    for (int i = 0; i < 4; ++i) {
#pragma unroll
      for (int r = 0; r < 4; ++r) {
        const int fr = m0 + wm + i * 16 + g * 4 + r;   // feature row 0..1023
        const float bv = bias[fr];
        const int h = fr >> 6, dd = fr & 63;
#pragma unroll
        for (int j = 0; j < 4; ++j) {
          const int tok = n0 + wn + j * 16 + d;
          const int b = tok >> 11, s = tok & 2047;
          O[(size_t)(((b << 4) + h) * 64 + dd) * 2048 + s] = f2b(acc[i][j][r] + bv);
        }
      }
    }
  } else {
    float* O = (float*)outp;
#pragma unroll
    for (int i = 0; i < 4; ++i) {
#pragma unroll
      for (int r = 0; r < 4; ++r) {
        const int m = m0 + wm + i * 16 + g * 4 + r;
#pragma unroll
        for (int j = 0; j < 4; ++j) {
          const int n = n0 + wn + j * 16 + d;
          O[(size_t)m * 1024 + n] = acc[i][j][r] + bias[n] + resid[(size_t)m * 1024 + n];
        }
      }
    }
  }
}

// ---------------- flash attention ----------------
// Q,K: (bh, s, 64) bf16 (q pre-scaled by log2e/64); VT: (bh, 64, s) bf16
// out ctx: (b*2048+s, h*64+hd) bf16. Grid (32 qblocks, 32 bh), 256 thr (4 waves x 16 rows).
__global__ __launch_bounds__(256) void attn_kernel(
    const ushort_t* __restrict__ Q, const ushort_t* __restrict__ Kb,
    const ushort_t* __restrict__ VT, ushort_t* __restrict__ ctx)
{
  __shared__ uint4 Ks[512], Vs[512], Ps[512];   // 8KB each
  const int bh = blockIdx.y;
  const int q0 = blockIdx.x * 64;
  const int tid = threadIdx.x, wave = tid >> 6, lane = tid & 63;
  const int d = lane & 15, g = lane >> 4;
  ushort_t* Pu = (ushort_t*)Ps;

  bf16x8 qf[2];
  {
    const ushort_t* qp = Q + (size_t)(bh * 2048 + q0 + wave * 16 + d) * 64 + g * 8;
    qf[0] = __builtin_bit_cast(bf16x8, *(const uint4*)qp);
    qf[1] = __builtin_bit_cast(bf16x8, *(const uint4*)(qp + 32));
  }

  float mreg[4] = {-1e30f, -1e30f, -1e30f, -1e30f};
  float lsum[4] = {0.f, 0.f, 0.f, 0.f};
  f32x4 cacc[4] = {};

  for (int kv0 = 0; kv0 < 2048; kv0 += 64) {
    __syncthreads();
#pragma unroll
    for (int it = 0; it < 2; ++it) {
      const int c = tid + it * 256;
      const int t = c >> 3, c8 = c & 7;   // t: row (kv for K, feature for VT)
      Ks[t * 8 + (c8 ^ (t & 7))] = *(const uint4*)(Kb + (size_t)(bh * 2048 + kv0 + t) * 64 + c8 * 8);
      Vs[t * 8 + (c8 ^ (t & 7))] = *(const uint4*)(VT + (size_t)(bh * 64 + t) * 2048 + kv0 + c8 * 8);
    }
    __syncthreads();

    // QK^T: sacc[j] lane,reg r = S'[qrow=g*4+r, kv=j*16+d]
    f32x4 sacc[4];
#pragma unroll
    for (int j = 0; j < 4; ++j) {
      f32x4 z = {};
#pragma unroll
      for (int sl = 0; sl < 2; ++sl) {
        bf16x8 kf = __builtin_bit_cast(bf16x8, Ks[(j * 16 + d) * 8 + ((g + 4 * sl) ^ (d & 7))]);
        z = __builtin_amdgcn_mfma_f32_16x16x32_bf16(qf[sl], kf, z, 0, 0, 0);
      }
      sacc[j] = z;
    }

    // online softmax (exp2 domain), rows g*4+r, reduce over 16 lanes of group
    float vmax[4], psum[4];
#pragma unroll
    for (int r = 0; r < 4; ++r)
      vmax[r] = fmaxf(fmaxf(sacc[0][r], sacc[1][r]), fmaxf(sacc[2][r], sacc[3][r]));
#pragma unroll
    for (int off = 1; off < 16; off <<= 1)
#pragma unroll
      for (int r = 0; r < 4; ++r)
        vmax[r] = fmaxf(vmax[r], __shfl_xor(vmax[r], off, 64));
#pragma unroll
    for (int r = 0; r < 4; ++r) {
      const float mn = fmaxf(mreg[r], vmax[r]);
      const float sc = exp2f(mreg[r] - mn);
      mreg[r] = mn;
      lsum[r] *= sc;
      cacc[0][r] *= sc; cacc[1][r] *= sc; cacc[2][r] *= sc; cacc[3][r] *= sc;
      psum[r] = 0.f;
    }
#pragma unroll
    for (int j = 0; j < 4; ++j)
#pragma unroll
      for (int r = 0; r < 4; ++r) {
        const float pp = exp2f(sacc[j][r] - mreg[r]);
        psum[r] += pp;
        const int row = g * 4 + r, col = j * 16 + d;
        Pu[wave * 1024 + row * 64 + ((((col >> 3)) ^ (row & 7)) << 3) + (col & 7)] = f2b(pp);
      }
#pragma unroll
    for (int off = 1; off < 16; off <<= 1)
#pragma unroll
      for (int r = 0; r < 4; ++r)
        psum[r] += __shfl_xor(psum[r], off, 64);
#pragma unroll
    for (int r = 0; r < 4; ++r) lsum[r] += psum[r];

    // cross-lane RAW on P through LDS: drain DS before reads
    asm volatile("s_waitcnt lgkmcnt(0)" ::: "memory");

    // PV: A = P (rows = qrow-local = d), B = V via VT rows
    bf16x8 pf[2];
#pragma unroll
    for (int sl = 0; sl < 2; ++sl)
      pf[sl] = __builtin_bit_cast(bf16x8, Ps[wave * 128 + d * 8 + ((g + 4 * sl) ^ (d & 7))]);
#pragma unroll
    for (int dt = 0; dt < 4; ++dt) {
#pragma unroll
      for (int sl = 0; sl < 2; ++sl) {
        bf16x8 vf = __builtin_bit_cast(bf16x8, Vs[(dt * 16 + d) * 8 + ((g + 4 * sl) ^ (d & 7))]);
        cacc[dt] = __builtin_amdgcn_mfma_f32_16x16x32_bf16(pf[sl], vf, cacc[dt], 0, 0, 0);
      }
    }
  }

  const int b = bh >> 4, h = bh & 15;
#pragma unroll
  for (int dt = 0; dt < 4; ++dt)
#pragma unroll
    for (int r = 0; r < 4; ++r) {
      const int qrow = q0 + wave * 16 + g * 4 + r;
      ctx[(size_t)(b * 2048 + qrow) * 1024 + h * 64 + dt * 16 + d] =
          f2b(cacc[dt][r] / lsum[r]);
    }
}

// ---------------- LayerNorm over rows of 1024 ----------------
__global__ __launch_bounds__(256) void ln_kernel(const float* __restrict__ x,
    const float* __restrict__ w, const float* __restrict__ b2, float* __restrict__ out)
{
  const int row = blockIdx.x, tid = threadIdx.x;
  const float4 v = ((const float4*)(x + (size_t)row * 1024))[tid];
  float s = v.x + v.y + v.z + v.w;
  float ss = v.x * v.x + v.y * v.y + v.z * v.z + v.w * v.w;
#pragma unroll
  for (int off = 32; off > 0; off >>= 1) {
    s += __shfl_down(s, off, 64);
    ss += __shfl_down(ss, off, 64);
  }
  __shared__ float red[8];
  if ((tid & 63) == 0) { red[tid >> 6] = s; red[4 + (tid >> 6)] = ss; }
  __syncthreads();
  const float S = red[0] + red[1] + red[2] + red[3];
  const float SS = red[4] + red[5] + red[6] + red[7];
  const float mu = S * (1.f / 1024.f);
  const float rstd = rsqrtf(SS * (1.f / 1024.f) - mu * mu + 1e-12f);
  const int c = tid * 4;
  float4 o;
  o.x = (v.x - mu) * rstd * w[c + 0] + b2[c + 0];
  o.y = (v.y - mu) * rstd * w[c + 1] + b2[c + 1];
  o.z = (v.z - mu) * rstd * w[c + 2] + b2[c + 2];
  o.w = (v.w - mu) * rstd * w[c + 3] + b2[c + 3];
  ((float4*)(out + (size_t)row * 1024))[tid] = o;
}

// ---------------- launch ----------------
extern "C" void kernel_launch(void* const* d_in, const int* in_sizes, int n_in,
                              void* d_out, int out_size, void* d_ws, size_t ws_size,
                              hipStream_t stream) {
  const float* hidden = (const float*)d_in[0];
  const float* cosT = (const float*)d_in[1];
  const float* sinT = (const float*)d_in[2];
  const float* Wq = (const float*)d_in[3];
  const float* bq = (const float*)d_in[4];
  const float* Wk = (const float*)d_in[5];
  const float* bk = (const float*)d_in[6];
  const float* Wv = (const float*)d_in[7];
  const float* bv = (const float*)d_in[8];
  const float* Wo = (const float*)d_in[9];
  const float* bo = (const float*)d_in[10];
  const float* lnw = (const float*)d_in[11];
  const float* lnb = (const float*)d_in[12];

  char* ws = (char*)d_ws;
  const size_t MB = 1u << 20;
  ushort_t* hid_bf = (ushort_t*)(ws);
  ushort_t* wq_bf = (ushort_t*)(ws + 8 * MB);
  ushort_t* wk_bf = (ushort_t*)(ws + 10 * MB);
  ushort_t* wv_bf = (ushort_t*)(ws + 12 * MB);
  ushort_t* wo_bf = (ushort_t*)(ws + 14 * MB);
  ushort_t* q_buf = (ushort_t*)(ws + 16 * MB);
  ushort_t* k_buf = (ushort_t*)(ws + 24 * MB);
  ushort_t* vt_buf = (ushort_t*)(ws + 32 * MB);
  ushort_t* ctx_bf = (ushort_t*)(ws + 40 * MB);
  float* out_pre = (float*)(ws + 16 * MB);   // aliases q+k (dead by then)

  cast_kernel<<<2048, 256, 0, stream>>>(hidden, hid_bf, 4194304);
  cast_kernel<<<512, 256, 0, stream>>>(Wq, wq_bf, 1048576);
  cast_kernel<<<512, 256, 0, stream>>>(Wk, wk_bf, 1048576);
  cast_kernel<<<512, 256, 0, stream>>>(Wv, wv_bf, 1048576);
  cast_kernel<<<512, 256, 0, stream>>>(Wo, wo_bf, 1048576);

  // Q: fold scaling^2 * log2e into q so attention works in exp2 domain
  gemm128<0><<<dim3(32, 8), 256, 0, stream>>>(hid_bf, wq_bf, bq, cosT, sinT, nullptr,
                                              q_buf, LOG2E / 64.0f);
  gemm128<0><<<dim3(32, 8), 256, 0, stream>>>(hid_bf, wk_bf, bk, cosT, sinT, nullptr,
                                              k_buf, 1.0f);
  gemm128<1><<<dim3(8, 32), 256, 0, stream>>>(wv_bf, hid_bf, bv, nullptr, nullptr, nullptr,
                                              vt_buf, 1.0f);
  attn_kernel<<<dim3(32, 32), 256, 0, stream>>>(q_buf, k_buf, vt_buf, ctx_bf);
  gemm128<2><<<dim3(32, 8), 256, 0, stream>>>(ctx_bf, wo_bf, bo, nullptr, nullptr, hidden,
                                              out_pre, 1.0f);
  ln_kernel<<<4096, 256, 0, stream>>>(out_pre, lnw, lnb, (float*)d_out);
}

// Round 2
// 185.086 us; speedup vs baseline: 1.3079x; 1.3079x over previous
//
#include <hip/hip_runtime.h>
#include <hip/hip_bf16.h>
#include <stdint.h>

// Problem constants: B=2, S=2048, D=1024, H=16, HD=64.
// ws layout (MB): 0 hid_bf | 8 wq | 10 wk | 12 wv | 14 wo | 16 q (8MB) | 24 k (8MB)
//                 | 32 vt (8MB) | 40 ctx (8MB);  out_pre(f32,16MB) aliases q+k @16MB.
// Total 48 MB.

typedef unsigned short ushort_t;
typedef short bf16x8 __attribute__((ext_vector_type(8)));
typedef float f32x4 __attribute__((ext_vector_type(4)));
typedef unsigned short ushort8 __attribute__((ext_vector_type(8)));

#define LOG2E 1.4426950408889634f

__device__ __forceinline__ ushort_t f2b(float f) {
  uint32_t x = __builtin_bit_cast(uint32_t, f);
  return (ushort_t)((x + 0x7FFFu + ((x >> 16) & 1u)) >> 16);
}

__device__ __forceinline__ uint32_t cvt_pk_bf16(float lo, float hi) {
  uint32_t r;
  asm("v_cvt_pk_bf16_f32 %0, %1, %2" : "=v"(r) : "v"(lo), "v"(hi));
  return r;
}

__device__ __forceinline__ void gload16(const void* gptr, void* ldsptr) {
  __builtin_amdgcn_global_load_lds(
      (const __attribute__((address_space(1))) uint32_t*)gptr,
      (__attribute__((address_space(3))) uint32_t*)ldsptr, 16, 0, 0);
}

// ---------------- casts fp32 -> bf16 (vectorized) ----------------
__global__ void cast_kernel(const float* __restrict__ src, ushort_t* __restrict__ dst, int n) {
  int i = (blockIdx.x * 256 + threadIdx.x) * 8;
  if (i >= n) return;
  const float4* s = (const float4*)(src + i);
  float4 a = s[0], b = s[1];
  ushort8 o = { f2b(a.x), f2b(a.y), f2b(a.z), f2b(a.w),
                f2b(b.x), f2b(b.y), f2b(b.z), f2b(b.w) };
  *(ushort8*)(dst + i) = o;
}

// 4 weight matrices (1M elems each) in one launch: 512 blocks per matrix
__global__ void cast4_kernel(const float* __restrict__ a, const float* __restrict__ b,
                             const float* __restrict__ c, const float* __restrict__ d2,
                             ushort_t* __restrict__ oa, ushort_t* __restrict__ ob,
                             ushort_t* __restrict__ oc, ushort_t* __restrict__ od) {
  const int which = blockIdx.x >> 9;
  const float* src = which == 0 ? a : which == 1 ? b : which == 2 ? c : d2;
  ushort_t* dst = which == 0 ? oa : which == 1 ? ob : which == 2 ? oc : od;
  int i = ((blockIdx.x & 511) * 256 + threadIdx.x) * 8;
  const float4* s = (const float4*)(src + i);
  float4 x = s[0], y = s[1];
  ushort8 o = { f2b(x.x), f2b(x.y), f2b(x.z), f2b(x.w),
                f2b(y.x), f2b(y.y), f2b(y.z), f2b(y.w) };
  *(ushort8*)(dst + i) = o;
}

// ---------------- GEMM 128x128, BK=32, 4 waves (m97 structure) ----------------
// C[m,n] = sum_k A[m,k]*B[n,k]   (A,B row-major [.][1024] bf16)
// MODE 0: QK proj: epilogue bias + RoPE (+qscale), out (bh,s,hd) bf16
// MODE 1: V^T: A=Wv, B=hidden; epilogue bias; out (bh,hd,s) bf16
// MODE 2: Wo: epilogue bias + residual, out fp32 [m][n]
template<int MODE>
__global__ __launch_bounds__(256) void gemm128(
    const ushort_t* __restrict__ A, const ushort_t* __restrict__ B,
    const float* __restrict__ bias, const float* __restrict__ cosT,
    const float* __restrict__ sinT, const float* __restrict__ resid,
    void* __restrict__ outp, float qscale)
{
  constexpr int K = 1024;
  __shared__ uint4 As[512], Bs[512];   // 128 rows x 4 chunks(16B) each
  const int tid = threadIdx.x;
  const int wave = tid >> 6, lane = tid & 63;
  const int d = lane & 15, g = lane >> 4;
  const int m0 = blockIdx.x * 128, n0 = blockIdx.y * 128;
  const int wm = (wave >> 1) * 64, wn = (wave & 1) * 64;

  const ushort_t* ag = A + (size_t)(m0 + (tid >> 2)) * K + (tid & 3) * 8;
  const ushort_t* bg = B + (size_t)(n0 + (tid >> 2)) * K + (tid & 3) * 8;
  char* asd = (char*)As + wave * 1024;   // wave-uniform LDS dest
  char* bsd = (char*)Bs + wave * 1024;

  f32x4 acc[4][4] = {};

  for (int k0 = 0; k0 < K; k0 += 32) {
    __syncthreads();
    gload16(ag + k0, asd);
    gload16(ag + 64 * K + k0, asd + 4096);
    gload16(bg + k0, bsd);
    gload16(bg + 64 * K + k0, bsd + 4096);
    __syncthreads();
    bf16x8 af[4], bfr[4];
#pragma unroll
    for (int i = 0; i < 4; ++i)
      af[i] = __builtin_bit_cast(bf16x8, As[(wm + i * 16 + d) * 4 + g]);
#pragma unroll
    for (int j = 0; j < 4; ++j)
      bfr[j] = __builtin_bit_cast(bf16x8, Bs[(wn + j * 16 + d) * 4 + g]);
#pragma unroll
    for (int i = 0; i < 4; ++i)
#pragma unroll
      for (int j = 0; j < 4; ++j)
        acc[i][j] = __builtin_amdgcn_mfma_f32_16x16x32_bf16(af[i], bfr[j], acc[i][j], 0, 0, 0);
  }

  // C/D layout: lane, reg r -> row = g*4+r, col = d (within each 16x16 tile)
  if constexpr (MODE == 0) {
    ushort_t* O = (ushort_t*)outp;
    const int head_base = n0 + wn;      // multiple of 64 -> single head per wave
    const int h = head_base >> 6;
#pragma unroll
    for (int i = 0; i < 4; ++i) {
#pragma unroll
      for (int r = 0; r < 4; ++r) {
        const int m = m0 + wm + i * 16 + g * 4 + r;
        const int s = m & 2047, b = m >> 11;
#pragma unroll
        for (int j = 0; j < 4; ++j) {
          const int c = j * 16 + d;     // 0..63 within head
          const float v0 = acc[i][j][r] + bias[head_base + c];
          const float v1 = acc[i][j ^ 2][r] + bias[head_base + (c ^ 32)];
          const float rot = (c < 32) ? -v1 : v1;
          const float vr = (v0 * cosT[s * 64 + c] + rot * sinT[s * 64 + c]) * qscale;
          O[(size_t)(((b << 4) + h) * 2048 + s) * 64 + c] = f2b(vr);
        }
      }
    }
  } else if constexpr (MODE == 1) {
    ushort_t* O = (ushort_t*)outp;
#pragma unroll
    for (int i = 0; i < 4; ++i) {
#pragma unroll
      for (int r = 0; r < 4; ++r) {
        const int fr = m0 + wm + i * 16 + g * 4 + r;   // feature row 0..1023
        const float bv = bias[fr];
        const int h = fr >> 6, dd = fr & 63;
#pragma unroll
        for (int j = 0; j < 4; ++j) {
          const int tok = n0 + wn + j * 16 + d;
          const int b = tok >> 11, s = tok & 2047;
          O[(size_t)(((b << 4) + h) * 64 + dd) * 2048 + s] = f2b(acc[i][j][r] + bv);
        }
      }
    }
  } else {
    float* O = (float*)outp;
#pragma unroll
    for (int i = 0; i < 4; ++i) {
#pragma unroll
      for (int r = 0; r < 4; ++r) {
        const int m = m0 + wm + i * 16 + g * 4 + r;
#pragma unroll
        for (int j = 0; j < 4; ++j) {
          const int n = n0 + wn + j * 16 + d;
          O[(size_t)m * 1024 + n] = acc[i][j][r] + bias[n] + resid[(size_t)m * 1024 + n];
        }
      }
    }
  }
}

// ---------------- flash attention (swapped QK^T, lane-local softmax) ----------------
// Q,K: (bh, s, 64) bf16 (q pre-scaled by log2e/64); VT: (bh, 64, s) bf16
// out ctx: (b*2048+s, h*64+hd) bf16. Grid (32 qblocks, 32 bh), 256 thr (4 waves x 16 q rows).
// Swapped QK^T: sacc = mfma(K, Q) -> lane (d,g) holds S[kv = 16j+4g+r, q = d].
// P exchanged through a per-wave XOR-swizzled LDS buffer (4x ds_write_b64, 2x ds_read_b128)
// to form the PV B-fragment P^T[kv = 32sl+8g..+7, q=d]. PV: A = V^T rows from LDS.
__global__ __launch_bounds__(256) void attn_kernel(
    const ushort_t* __restrict__ Q, const ushort_t* __restrict__ Kb,
    const ushort_t* __restrict__ VT, ushort_t* __restrict__ ctx)
{
  __shared__ uint4 Ks[512], Vs[512];   // 8KB each, 64 rows x 8 chunks(16B), chunk^(row&7)
  __shared__ uint4 Ps[512];            // 8KB: 4 waves x 16 q-rows x 128B, u32-chunk ^((d&7)<<2)
  const int bh = blockIdx.y;
  const int q0 = blockIdx.x * 64;
  const int tid = threadIdx.x, wave = tid >> 6, lane = tid & 63;
  const int d = lane & 15, g = lane >> 4;
  const int dsw = (d & 7) << 2;
  char* Pbase = (char*)Ps + wave * 2048 + d * 128;

  // Q fragment (B operand): lane holds Q[q = d][hd = 32*sl + 8g .. +7]
  bf16x8 qf[2];
  {
    const ushort_t* qp = Q + (size_t)(bh * 2048 + q0 + wave * 16 + d) * 64 + g * 8;
    qf[0] = __builtin_bit_cast(bf16x8, *(const uint4*)qp);
    qf[1] = __builtin_bit_cast(bf16x8, *(const uint4*)(qp + 32));
  }

  // staging: each thread owns (row = tid>>3 [+32], chunk c8 = tid&7) for K and V tiles
  const int st_row = tid >> 3, st_c8 = tid & 7;
  const ushort_t* kgp = Kb + (size_t)(bh * 2048 + st_row) * 64 + st_c8 * 8;
  const ushort_t* vgp = VT + (size_t)(bh * 64 + st_row) * 2048 + st_c8 * 8;
  const int sidx0 = st_row * 8 + (st_c8 ^ (st_row & 7));
  const int sidx1 = (st_row + 32) * 8 + (st_c8 ^ (st_row & 7));

  uint4 kr0, kr1, vr0, vr1;
  kr0 = *(const uint4*)(kgp);
  kr1 = *(const uint4*)(kgp + 32 * 64);
  vr0 = *(const uint4*)(vgp);
  vr1 = *(const uint4*)(vgp + 32 * 2048);

  float mreg = -1e30f, lsum = 0.f;
  f32x4 cacc[4] = {};

  for (int kv0 = 0; kv0 < 2048; kv0 += 64) {
    __syncthreads();                 // all waves done reading previous tile
    Ks[sidx0] = kr0; Ks[sidx1] = kr1;
    Vs[sidx0] = vr0; Vs[sidx1] = vr1;
    __syncthreads();
    if (kv0 + 64 < 2048) {           // prefetch next tile (overlaps compute)
      kr0 = *(const uint4*)(kgp + (kv0 + 64) * 64);
      kr1 = *(const uint4*)(kgp + (kv0 + 96) * 64);
      vr0 = *(const uint4*)(vgp + kv0 + 64);
      vr1 = *(const uint4*)(vgp + 32 * 2048 + kv0 + 64);
    }

    // QK^T swapped: A = K rows (kv), B = Q cols (q)
    f32x4 sacc[4];
#pragma unroll
    for (int j = 0; j < 4; ++j) {
      f32x4 z = {};
#pragma unroll
      for (int sl = 0; sl < 2; ++sl) {
        bf16x8 kf = __builtin_bit_cast(bf16x8, Ks[(j * 16 + d) * 8 + ((g + 4 * sl) ^ (d & 7))]);
        z = __builtin_amdgcn_mfma_f32_16x16x32_bf16(kf, qf[sl], z, 0, 0, 0);
      }
      sacc[j] = z;
    }

    // lane-local row max (q = d), then across the 4 g-groups
    float vmax = -1e30f;
#pragma unroll
    for (int j = 0; j < 4; ++j) {
      float mj = fmaxf(fmaxf(sacc[j][0], sacc[j][1]), fmaxf(sacc[j][2], sacc[j][3]));
      vmax = fmaxf(vmax, mj);
    }
    vmax = fmaxf(vmax, __shfl_xor(vmax, 16, 64));
    vmax = fmaxf(vmax, __shfl_xor(vmax, 32, 64));

    // defer-max: only rescale when the max moved by > 8 (exp2 units)
    if (__any(vmax > mreg + 8.0f)) {
      const float mn = fmaxf(mreg, vmax);
      const float sc = exp2f(mreg - mn);
      mreg = mn;
      lsum *= sc;
#pragma unroll
      for (int dt = 0; dt < 4; ++dt) {
        cacc[dt][0] *= sc; cacc[dt][1] *= sc; cacc[dt][2] *= sc; cacc[dt][3] *= sc;
      }
    }

    // P = exp2(S - m); per-lane partial row sum (reduced across g at the end)
    float ps = 0.f;
#pragma unroll
    for (int j = 0; j < 4; ++j) {
      float p0 = exp2f(sacc[j][0] - mreg);
      float p1 = exp2f(sacc[j][1] - mreg);
      float p2 = exp2f(sacc[j][2] - mreg);
      float p3 = exp2f(sacc[j][3] - mreg);
      ps += (p0 + p1) + (p2 + p3);
      uint2 w;
      w.x = cvt_pk_bf16(p0, p1);
      w.y = cvt_pk_bf16(p2, p3);
      // kv chunk pair (8j+2g) ^ swz  (conflict-free b64 across the wave)
      *(uint2*)(Pbase + (((8 * j + 2 * g) ^ dsw) << 2)) = w;
    }
    lsum += ps;

    asm volatile("s_waitcnt lgkmcnt(0)" ::: "memory");
    __builtin_amdgcn_sched_barrier(0);

    // PV: A = V^T[hd, kv] rows from LDS, B = P^T[kv, q=d] fragments from P buffer
    bf16x8 pf[2];
#pragma unroll
    for (int sl = 0; sl < 2; ++sl)
      pf[sl] = __builtin_bit_cast(bf16x8, *(const uint4*)(Pbase + (((16 * sl + 4 * g) ^ dsw) << 2)));
#pragma unroll
    for (int dt = 0; dt < 4; ++dt) {
#pragma unroll
      for (int sl = 0; sl < 2; ++sl) {
        bf16x8 vf = __builtin_bit_cast(bf16x8, Vs[(dt * 16 + d) * 8 + ((g + 4 * sl) ^ (d & 7))]);
        cacc[dt] = __builtin_amdgcn_mfma_f32_16x16x32_bf16(vf, pf[sl], cacc[dt], 0, 0, 0);
      }
    }
  }

  // final row sum across g-groups; output ctx^T fragments
  lsum += __shfl_xor(lsum, 16, 64);
  lsum += __shfl_xor(lsum, 32, 64);
  const float rinv = 1.0f / lsum;
  const int b = bh >> 4, h = bh & 15;
  ushort_t* cp = ctx + (size_t)(b * 2048 + q0 + wave * 16 + d) * 1024 + h * 64;
#pragma unroll
  for (int dt = 0; dt < 4; ++dt) {
    uint2 w;
    w.x = cvt_pk_bf16(cacc[dt][0] * rinv, cacc[dt][1] * rinv);
    w.y = cvt_pk_bf16(cacc[dt][2] * rinv, cacc[dt][3] * rinv);
    *(uint2*)(cp + dt * 16 + g * 4) = w;
  }
}

// ---------------- LayerNorm over rows of 1024 ----------------
__global__ __launch_bounds__(256) void ln_kernel(const float* __restrict__ x,
    const float* __restrict__ w, const float* __restrict__ b2, float* __restrict__ out)
{
  const int row = blockIdx.x, tid = threadIdx.x;
  const float4 v = ((const float4*)(x + (size_t)row * 1024))[tid];
  float s = v.x + v.y + v.z + v.w;
  float ss = v.x * v.x + v.y * v.y + v.z * v.z + v.w * v.w;
#pragma unroll
  for (int off = 32; off > 0; off >>= 1) {
    s += __shfl_down(s, off, 64);
    ss += __shfl_down(ss, off, 64);
  }
  __shared__ float red[8];
  if ((tid & 63) == 0) { red[tid >> 6] = s; red[4 + (tid >> 6)] = ss; }
  __syncthreads();
  const float S = red[0] + red[1] + red[2] + red[3];
  const float SS = red[4] + red[5] + red[6] + red[7];
  const float mu = S * (1.f / 1024.f);
  const float rstd = rsqrtf(SS * (1.f / 1024.f) - mu * mu + 1e-12f);
  const int c = tid * 4;
  float4 o;
  o.x = (v.x - mu) * rstd * w[c + 0] + b2[c + 0];
  o.y = (v.y - mu) * rstd * w[c + 1] + b2[c + 1];
  o.z = (v.z - mu) * rstd * w[c + 2] + b2[c + 2];
  o.w = (v.w - mu) * rstd * w[c + 3] + b2[c + 3];
  ((float4*)(out + (size_t)row * 1024))[tid] = o;
}

// ---------------- launch ----------------
extern "C" void kernel_launch(void* const* d_in, const int* in_sizes, int n_in,
                              void* d_out, int out_size, void* d_ws, size_t ws_size,
                              hipStream_t stream) {
  const float* hidden = (const float*)d_in[0];
  const float* cosT = (const float*)d_in[1];
  const float* sinT = (const float*)d_in[2];
  const float* Wq = (const float*)d_in[3];
  const float* bq = (const float*)d_in[4];
  const float* Wk = (const float*)d_in[5];
  const float* bk = (const float*)d_in[6];
  const float* Wv = (const float*)d_in[7];
  const float* bv = (const float*)d_in[8];
  const float* Wo = (const float*)d_in[9];
  const float* bo = (const float*)d_in[10];
  const float* lnw = (const float*)d_in[11];
  const float* lnb = (const float*)d_in[12];

  char* ws = (char*)d_ws;
  const size_t MB = 1u << 20;
  ushort_t* hid_bf = (ushort_t*)(ws);
  ushort_t* wq_bf = (ushort_t*)(ws + 8 * MB);
  ushort_t* wk_bf = (ushort_t*)(ws + 10 * MB);
  ushort_t* wv_bf = (ushort_t*)(ws + 12 * MB);
  ushort_t* wo_bf = (ushort_t*)(ws + 14 * MB);
  ushort_t* q_buf = (ushort_t*)(ws + 16 * MB);
  ushort_t* k_buf = (ushort_t*)(ws + 24 * MB);
  ushort_t* vt_buf = (ushort_t*)(ws + 32 * MB);
  ushort_t* ctx_bf = (ushort_t*)(ws + 40 * MB);
  float* out_pre = (float*)(ws + 16 * MB);   // aliases q+k (dead by then)

  cast_kernel<<<2048, 256, 0, stream>>>(hidden, hid_bf, 4194304);
  cast4_kernel<<<2048, 256, 0, stream>>>(Wq, Wk, Wv, Wo, wq_bf, wk_bf, wv_bf, wo_bf);

  // Q: fold scaling^2 * log2e into q so attention works in exp2 domain
  gemm128<0><<<dim3(32, 8), 256, 0, stream>>>(hid_bf, wq_bf, bq, cosT, sinT, nullptr,
                                              q_buf, LOG2E / 64.0f);
  gemm128<0><<<dim3(32, 8), 256, 0, stream>>>(hid_bf, wk_bf, bk, cosT, sinT, nullptr,
                                              k_buf, 1.0f);
  gemm128<1><<<dim3(8, 32), 256, 0, stream>>>(wv_bf, hid_bf, bv, nullptr, nullptr, nullptr,
                                              vt_buf, 1.0f);
  attn_kernel<<<dim3(32, 32), 256, 0, stream>>>(q_buf, k_buf, vt_buf, ctx_bf);
  gemm128<2><<<dim3(32, 8), 256, 0, stream>>>(ctx_bf, wo_bf, bo, nullptr, nullptr, hidden,
                                              out_pre, 1.0f);
  ln_kernel<<<4096, 256, 0, stream>>>(out_pre, lnw, lnb, (float*)d_out);
}

// Round 3
// 168.776 us; speedup vs baseline: 1.4343x; 1.0966x over previous
//
#include <hip/hip_runtime.h>
#include <hip/hip_bf16.h>
#include <stdint.h>

// Problem constants: B=2, S=2048, D=1024, H=16, HD=64.
// ws layout (MB): 0 hid_bf | 8 wq | 10 wk | 12 wv | 14 wo | 16 q (8MB) | 24 k (8MB)
//                 | 32 vt (8MB) | 40 ctx (8MB);  out_pre(f32,16MB) aliases q+k @16MB.

typedef unsigned short ushort_t;
typedef short bf16x8 __attribute__((ext_vector_type(8)));
typedef float f32x4 __attribute__((ext_vector_type(4)));
typedef float f32x16 __attribute__((ext_vector_type(16)));
typedef unsigned short ushort8 __attribute__((ext_vector_type(8)));

#define LOG2E 1.4426950408889634f

__device__ __forceinline__ ushort_t f2b(float f) {
  uint32_t x = __builtin_bit_cast(uint32_t, f);
  return (ushort_t)((x + 0x7FFFu + ((x >> 16) & 1u)) >> 16);
}

__device__ __forceinline__ uint32_t cvt_pk_bf16(float lo, float hi) {
  uint32_t r;
  asm("v_cvt_pk_bf16_f32 %0, %1, %2" : "=v"(r) : "v"(lo), "v"(hi));
  return r;
}

// S1 semantics: a.upper <-> b.lower.  After call:
//   a = {a(l) for l<32,  b(l-32) for l>=32}
//   b = {a(l+32) for l<32,  b(l) for l>=32}
__device__ __forceinline__ void permswap(uint32_t& a, uint32_t& b) {
  asm volatile("v_permlane32_swap_b32 %0, %1" : "+v"(a), "+v"(b));
}

__device__ __forceinline__ void gload16(const void* gptr, void* ldsptr) {
  __builtin_amdgcn_global_load_lds(
      (const __attribute__((address_space(1))) uint32_t*)gptr,
      (__attribute__((address_space(3))) uint32_t*)ldsptr, 16, 0, 0);
}

// ---------------- casts fp32 -> bf16 (vectorized) ----------------
__global__ void cast_kernel(const float* __restrict__ src, ushort_t* __restrict__ dst, int n) {
  int i = (blockIdx.x * 256 + threadIdx.x) * 8;
  if (i >= n) return;
  const float4* s = (const float4*)(src + i);
  float4 a = s[0], b = s[1];
  ushort8 o = { f2b(a.x), f2b(a.y), f2b(a.z), f2b(a.w),
                f2b(b.x), f2b(b.y), f2b(b.z), f2b(b.w) };
  *(ushort8*)(dst + i) = o;
}

__global__ void cast4_kernel(const float* __restrict__ a, const float* __restrict__ b,
                             const float* __restrict__ c, const float* __restrict__ d2,
                             ushort_t* __restrict__ oa, ushort_t* __restrict__ ob,
                             ushort_t* __restrict__ oc, ushort_t* __restrict__ od) {
  const int which = blockIdx.x >> 9;
  const float* src = which == 0 ? a : which == 1 ? b : which == 2 ? c : d2;
  ushort_t* dst = which == 0 ? oa : which == 1 ? ob : which == 2 ? oc : od;
  int i = ((blockIdx.x & 511) * 256 + threadIdx.x) * 8;
  const float4* s = (const float4*)(src + i);
  float4 x = s[0], y = s[1];
  ushort8 o = { f2b(x.x), f2b(x.y), f2b(x.z), f2b(x.w),
                f2b(y.x), f2b(y.y), f2b(y.z), f2b(y.w) };
  *(ushort8*)(dst + i) = o;
}

// ---------------- fused QKV projection GEMM (128x128 tile, BK=32, 4 waves) ----
// which = blockIdx.z: 0 -> Q (RoPE + scale), 1 -> K (RoPE), 2 -> V^T
__global__ __launch_bounds__(256) void gemm_qkv(
    const ushort_t* __restrict__ hid, const ushort_t* __restrict__ wq,
    const ushort_t* __restrict__ wk, const ushort_t* __restrict__ wv,
    const float* __restrict__ bq, const float* __restrict__ bk,
    const float* __restrict__ bv, const float* __restrict__ cosT,
    const float* __restrict__ sinT, ushort_t* __restrict__ qout,
    ushort_t* __restrict__ kout, ushort_t* __restrict__ vtout)
{
  constexpr int K = 1024;
  __shared__ uint4 As[512], Bs[512];
  const int which = blockIdx.z;
  const ushort_t* A;
  const ushort_t* Bm;
  const float* bias;
  int m0, n0;
  if (which == 0)      { A = hid; Bm = wq; bias = bq; m0 = blockIdx.x * 128; n0 = blockIdx.y * 128; }
  else if (which == 1) { A = hid; Bm = wk; bias = bk; m0 = blockIdx.x * 128; n0 = blockIdx.y * 128; }
  else                 { A = wv;  Bm = hid; bias = bv; m0 = blockIdx.y * 128; n0 = blockIdx.x * 128; }

  const int tid = threadIdx.x;
  const int wave = tid >> 6, lane = tid & 63;
  const int d = lane & 15, g = lane >> 4;
  const int wm = (wave >> 1) * 64, wn = (wave & 1) * 64;

  const ushort_t* ag = A + (size_t)(m0 + (tid >> 2)) * K + (tid & 3) * 8;
  const ushort_t* bg = Bm + (size_t)(n0 + (tid >> 2)) * K + (tid & 3) * 8;
  char* asd = (char*)As + wave * 1024;
  char* bsd = (char*)Bs + wave * 1024;

  f32x4 acc[4][4] = {};

  for (int k0 = 0; k0 < K; k0 += 32) {
    __syncthreads();
    gload16(ag + k0, asd);
    gload16(ag + 64 * K + k0, asd + 4096);
    gload16(bg + k0, bsd);
    gload16(bg + 64 * K + k0, bsd + 4096);
    __syncthreads();
    bf16x8 af[4], bfr[4];
#pragma unroll
    for (int i = 0; i < 4; ++i)
      af[i] = __builtin_bit_cast(bf16x8, As[(wm + i * 16 + d) * 4 + g]);
#pragma unroll
    for (int j = 0; j < 4; ++j)
      bfr[j] = __builtin_bit_cast(bf16x8, Bs[(wn + j * 16 + d) * 4 + g]);
#pragma unroll
    for (int i = 0; i < 4; ++i)
#pragma unroll
      for (int j = 0; j < 4; ++j)
        acc[i][j] = __builtin_amdgcn_mfma_f32_16x16x32_bf16(af[i], bfr[j], acc[i][j], 0, 0, 0);
  }

  if (which <= 1) {
    ushort_t* O = which == 0 ? qout : kout;
    const float qscale = which == 0 ? (LOG2E / 64.0f) : 1.0f;
    const int head_base = n0 + wn;
    const int h = head_base >> 6;
#pragma unroll
    for (int i = 0; i < 4; ++i) {
#pragma unroll
      for (int r = 0; r < 4; ++r) {
        const int m = m0 + wm + i * 16 + g * 4 + r;
        const int s = m & 2047, b = m >> 11;
#pragma unroll
        for (int j = 0; j < 4; ++j) {
          const int c = j * 16 + d;
          const float v0 = acc[i][j][r] + bias[head_base + c];
          const float v1 = acc[i][j ^ 2][r] + bias[head_base + (c ^ 32)];
          const float rot = (c < 32) ? -v1 : v1;
          const float vr = (v0 * cosT[s * 64 + c] + rot * sinT[s * 64 + c]) * qscale;
          O[(size_t)(((b << 4) + h) * 2048 + s) * 64 + c] = f2b(vr);
        }
      }
    }
  } else {
    ushort_t* O = vtout;
#pragma unroll
    for (int i = 0; i < 4; ++i) {
#pragma unroll
      for (int r = 0; r < 4; ++r) {
        const int fr = m0 + wm + i * 16 + g * 4 + r;
        const float bv2 = bias[fr];
        const int h = fr >> 6, dd = fr & 63;
#pragma unroll
        for (int j = 0; j < 4; ++j) {
          const int tok = n0 + wn + j * 16 + d;
          const int b = tok >> 11, s = tok & 2047;
          O[(size_t)(((b << 4) + h) * 64 + dd) * 2048 + s] = f2b(acc[i][j][r] + bv2);
        }
      }
    }
  }
}

// ---------------- Wo GEMM (bias + residual, fp32 out) ----------------
__global__ __launch_bounds__(256) void gemm_wo(
    const ushort_t* __restrict__ A, const ushort_t* __restrict__ B,
    const float* __restrict__ bias, const float* __restrict__ resid,
    float* __restrict__ O)
{
  constexpr int K = 1024;
  __shared__ uint4 As[512], Bs[512];
  const int tid = threadIdx.x;
  const int wave = tid >> 6, lane = tid & 63;
  const int d = lane & 15, g = lane >> 4;
  const int m0 = blockIdx.x * 128, n0 = blockIdx.y * 128;
  const int wm = (wave >> 1) * 64, wn = (wave & 1) * 64;

  const ushort_t* ag = A + (size_t)(m0 + (tid >> 2)) * K + (tid & 3) * 8;
  const ushort_t* bg = B + (size_t)(n0 + (tid >> 2)) * K + (tid & 3) * 8;
  char* asd = (char*)As + wave * 1024;
  char* bsd = (char*)Bs + wave * 1024;

  f32x4 acc[4][4] = {};

  for (int k0 = 0; k0 < K; k0 += 32) {
    __syncthreads();
    gload16(ag + k0, asd);
    gload16(ag + 64 * K + k0, asd + 4096);
    gload16(bg + k0, bsd);
    gload16(bg + 64 * K + k0, bsd + 4096);
    __syncthreads();
    bf16x8 af[4], bfr[4];
#pragma unroll
    for (int i = 0; i < 4; ++i)
      af[i] = __builtin_bit_cast(bf16x8, As[(wm + i * 16 + d) * 4 + g]);
#pragma unroll
    for (int j = 0; j < 4; ++j)
      bfr[j] = __builtin_bit_cast(bf16x8, Bs[(wn + j * 16 + d) * 4 + g]);
#pragma unroll
    for (int i = 0; i < 4; ++i)
#pragma unroll
      for (int j = 0; j < 4; ++j)
        acc[i][j] = __builtin_amdgcn_mfma_f32_16x16x32_bf16(af[i], bfr[j], acc[i][j], 0, 0, 0);
  }

#pragma unroll
  for (int i = 0; i < 4; ++i)
#pragma unroll
    for (int r = 0; r < 4; ++r) {
      const int m = m0 + wm + i * 16 + g * 4 + r;
#pragma unroll
      for (int j = 0; j < 4; ++j) {
        const int n = n0 + wn + j * 16 + d;
        O[(size_t)m * 1024 + n] = acc[i][j][r] + bias[n] + resid[(size_t)m * 1024 + n];
      }
    }
}

// ---------------- flash attention: 32x32 MFMA, in-register P exchange --------
// Q,K: (bh, s, 64) bf16 (q pre-scaled log2e/64); VT: (bh, 64, s) bf16
// Grid (16 qblocks x 32 bh), 256 thr = 4 waves x 32 q-rows. KVBLK=64.
// Swapped QK^T (mfma 32x32x16, A=K, B=Q): lane l holds S[kv=32jj+cr(r,h2)][q=l&31],
// cr = (r&3)+8*(r>>2)+4*h2.  Softmax lane-local; P -> PV B-frag via cvt_pk +
// permlane32_swap (no LDS).  PV: A = V^T rows from LDS.
__global__ __launch_bounds__(256) void attn_kernel(
    const ushort_t* __restrict__ Q, const ushort_t* __restrict__ Kb,
    const ushort_t* __restrict__ VT, ushort_t* __restrict__ ctx)
{
  __shared__ uint4 Ks[512], Vs[512];   // 8KB each: 64 rows x 8 chunks, chunk^(row&7)
  const int bh = blockIdx.y;
  const int q0 = blockIdx.x * 128;
  const int tid = threadIdx.x, wave = tid >> 6, lane = tid & 63;
  const int ql = lane & 31, h2 = lane >> 5;
  const int qrow = q0 + wave * 32 + ql;

  // Q fragments (B operand): qf[s] = Q[qrow][16s + 8*h2 .. +7]
  bf16x8 qf[4];
  {
    const ushort_t* qp = Q + ((size_t)bh * 2048 + qrow) * 64 + h2 * 8;
#pragma unroll
    for (int s = 0; s < 4; ++s)
      qf[s] = __builtin_bit_cast(bf16x8, *(const uint4*)(qp + 16 * s));
  }

  // staging: thread owns rows (tid>>3, tid>>3+32), chunk tid&7, for K and V tiles
  const int st_row = tid >> 3, st_c8 = tid & 7;
  const ushort_t* kgp = Kb + (size_t)(bh * 2048 + st_row) * 64 + st_c8 * 8;
  const ushort_t* vgp = VT + (size_t)(bh * 64 + st_row) * 2048 + st_c8 * 8;
  const int sidx0 = st_row * 8 + (st_c8 ^ (st_row & 7));
  const int sidx1 = (st_row + 32) * 8 + (st_c8 ^ (st_row & 7));

  uint4 kr0 = *(const uint4*)(kgp);
  uint4 kr1 = *(const uint4*)(kgp + 32 * 64);
  uint4 vr0 = *(const uint4*)(vgp);
  uint4 vr1 = *(const uint4*)(vgp + 32 * 2048);

  float mreg = -1e30f, lsum = 0.f;
  f32x16 cacc[2] = {};

  for (int kv0 = 0; kv0 < 2048; kv0 += 64) {
    __syncthreads();
    Ks[sidx0] = kr0; Ks[sidx1] = kr1;
    Vs[sidx0] = vr0; Vs[sidx1] = vr1;
    __syncthreads();
    if (kv0 + 64 < 2048) {
      kr0 = *(const uint4*)(kgp + (kv0 + 64) * 64);
      kr1 = *(const uint4*)(kgp + (kv0 + 96) * 64);
      vr0 = *(const uint4*)(vgp + kv0 + 64);
      vr1 = *(const uint4*)(vgp + 32 * 2048 + kv0 + 64);
    }

    // QK^T: per jj (kv 32-subtile), accumulate over 4 hd-slices
    f32x16 sacc[2];
#pragma unroll
    for (int jj = 0; jj < 2; ++jj) {
      f32x16 z = {};
#pragma unroll
      for (int s = 0; s < 4; ++s) {
        bf16x8 kf = __builtin_bit_cast(bf16x8,
            Ks[(jj * 32 + ql) * 8 + ((2 * s + h2) ^ (ql & 7))]);
        z = __builtin_amdgcn_mfma_f32_32x32x16_bf16(kf, qf[s], z, 0, 0, 0);
      }
      sacc[jj] = z;
    }

    // lane-local max over 32 scores, then cross-half
    float vmax = sacc[0][0];
#pragma unroll
    for (int jj = 0; jj < 2; ++jj)
#pragma unroll
      for (int r = 0; r < 16; ++r)
        vmax = fmaxf(vmax, sacc[jj][r]);
    vmax = fmaxf(vmax, __shfl_xor(vmax, 32, 64));

    // defer-max (THR=8 in exp2 units)
    if (__any(vmax > mreg + 8.0f)) {
      const float mn = fmaxf(mreg, vmax);
      const float sc = exp2f(mreg - mn);
      mreg = mn;
      lsum *= sc;
      cacc[0] *= sc;
      cacc[1] *= sc;
    }

    // exp -> pack -> permlane swap -> PV B-fragments (kv-run 16s+8*h2..+7, q=ql)
    bf16x8 pf[4];
    float ps = 0.f;
#pragma unroll
    for (int s = 0; s < 4; ++s) {
      const int jj = s >> 1;
      const int rb = (s & 1) * 8;
      float p0 = exp2f(sacc[jj][rb + 0] - mreg);
      float p1 = exp2f(sacc[jj][rb + 1] - mreg);
      float p2 = exp2f(sacc[jj][rb + 2] - mreg);
      float p3 = exp2f(sacc[jj][rb + 3] - mreg);
      float p4 = exp2f(sacc[jj][rb + 4] - mreg);
      float p5 = exp2f(sacc[jj][rb + 5] - mreg);
      float p6 = exp2f(sacc[jj][rb + 6] - mreg);
      float p7 = exp2f(sacc[jj][rb + 7] - mreg);
      ps += ((p0 + p1) + (p2 + p3)) + ((p4 + p5) + (p6 + p7));
      uint32_t a1 = cvt_pk_bf16(p0, p1);
      uint32_t a2 = cvt_pk_bf16(p2, p3);
      uint32_t b1 = cvt_pk_bf16(p4, p5);
      uint32_t b2 = cvt_pk_bf16(p6, p7);
      permswap(a1, b1);   // a1: own low / partner's low-of-high ; b1: mirrored
      permswap(a2, b2);
      uint4 u = {a1, a2, b1, b2};
      pf[s] = __builtin_bit_cast(bf16x8, u);
    }
    lsum += ps;

    // PV: A = V^T rows (hd = 32dt + ql), B = P fragments
#pragma unroll
    for (int dt = 0; dt < 2; ++dt)
#pragma unroll
      for (int s = 0; s < 4; ++s) {
        bf16x8 vf = __builtin_bit_cast(bf16x8,
            Vs[(dt * 32 + ql) * 8 + ((2 * s + h2) ^ (ql & 7))]);
        cacc[dt] = __builtin_amdgcn_mfma_f32_32x32x16_bf16(vf, pf[s], cacc[dt], 0, 0, 0);
      }
  }

  // finish: cross-half row sum, normalize, store ctx (token, h*64+hd)
  lsum += __shfl_xor(lsum, 32, 64);
  const float rinv = 1.0f / lsum;
  const int b = bh >> 4, h = bh & 15;
  ushort_t* cp = ctx + ((size_t)(b * 2048 + qrow)) * 1024 + h * 64 + h2 * 4;
#pragma unroll
  for (int dt = 0; dt < 2; ++dt)
#pragma unroll
    for (int t = 0; t < 4; ++t) {
      uint2 w;
      w.x = cvt_pk_bf16(cacc[dt][4 * t + 0] * rinv, cacc[dt][4 * t + 1] * rinv);
      w.y = cvt_pk_bf16(cacc[dt][4 * t + 2] * rinv, cacc[dt][4 * t + 3] * rinv);
      *(uint2*)(cp + dt * 32 + t * 8) = w;   // hd = 32dt + 8t + 4h2 + 0..3
    }
}

// ---------------- LayerNorm over rows of 1024 ----------------
__global__ __launch_bounds__(256) void ln_kernel(const float* __restrict__ x,
    const float* __restrict__ w, const float* __restrict__ b2, float* __restrict__ out)
{
  const int row = blockIdx.x, tid = threadIdx.x;
  const float4 v = ((const float4*)(x + (size_t)row * 1024))[tid];
  float s = v.x + v.y + v.z + v.w;
  float ss = v.x * v.x + v.y * v.y + v.z * v.z + v.w * v.w;
#pragma unroll
  for (int off = 32; off > 0; off >>= 1) {
    s += __shfl_down(s, off, 64);
    ss += __shfl_down(ss, off, 64);
  }
  __shared__ float red[8];
  if ((tid & 63) == 0) { red[tid >> 6] = s; red[4 + (tid >> 6)] = ss; }
  __syncthreads();
  const float S = red[0] + red[1] + red[2] + red[3];
  const float SS = red[4] + red[5] + red[6] + red[7];
  const float mu = S * (1.f / 1024.f);
  const float rstd = rsqrtf(SS * (1.f / 1024.f) - mu * mu + 1e-12f);
  const int c = tid * 4;
  float4 o;
  o.x = (v.x - mu) * rstd * w[c + 0] + b2[c + 0];
  o.y = (v.y - mu) * rstd * w[c + 1] + b2[c + 1];
  o.z = (v.z - mu) * rstd * w[c + 2] + b2[c + 2];
  o.w = (v.w - mu) * rstd * w[c + 3] + b2[c + 3];
  ((float4*)(out + (size_t)row * 1024))[tid] = o;
}

// ---------------- launch ----------------
extern "C" void kernel_launch(void* const* d_in, const int* in_sizes, int n_in,
                              void* d_out, int out_size, void* d_ws, size_t ws_size,
                              hipStream_t stream) {
  const float* hidden = (const float*)d_in[0];
  const float* cosT = (const float*)d_in[1];
  const float* sinT = (const float*)d_in[2];
  const float* Wq = (const float*)d_in[3];
  const float* bq = (const float*)d_in[4];
  const float* Wk = (const float*)d_in[5];
  const float* bk = (const float*)d_in[6];
  const float* Wv = (const float*)d_in[7];
  const float* bv = (const float*)d_in[8];
  const float* Wo = (const float*)d_in[9];
  const float* bo = (const float*)d_in[10];
  const float* lnw = (const float*)d_in[11];
  const float* lnb = (const float*)d_in[12];

  char* ws = (char*)d_ws;
  const size_t MB = 1u << 20;
  ushort_t* hid_bf = (ushort_t*)(ws);
  ushort_t* wq_bf = (ushort_t*)(ws + 8 * MB);
  ushort_t* wk_bf = (ushort_t*)(ws + 10 * MB);
  ushort_t* wv_bf = (ushort_t*)(ws + 12 * MB);
  ushort_t* wo_bf = (ushort_t*)(ws + 14 * MB);
  ushort_t* q_buf = (ushort_t*)(ws + 16 * MB);
  ushort_t* k_buf = (ushort_t*)(ws + 24 * MB);
  ushort_t* vt_buf = (ushort_t*)(ws + 32 * MB);
  ushort_t* ctx_bf = (ushort_t*)(ws + 40 * MB);
  float* out_pre = (float*)(ws + 16 * MB);   // aliases q+k (dead by then)

  cast_kernel<<<2048, 256, 0, stream>>>(hidden, hid_bf, 4194304);
  cast4_kernel<<<2048, 256, 0, stream>>>(Wq, Wk, Wv, Wo, wq_bf, wk_bf, wv_bf, wo_bf);

  gemm_qkv<<<dim3(32, 8, 3), 256, 0, stream>>>(hid_bf, wq_bf, wk_bf, wv_bf,
                                               bq, bk, bv, cosT, sinT,
                                               q_buf, k_buf, vt_buf);
  attn_kernel<<<dim3(16, 32), 256, 0, stream>>>(q_buf, k_buf, vt_buf, ctx_bf);
  gemm_wo<<<dim3(32, 8), 256, 0, stream>>>(ctx_bf, wo_bf, bo, hidden, out_pre);
  ln_kernel<<<4096, 256, 0, stream>>>(out_pre, lnw, lnb, (float*)d_out);
}